// Round 1
// baseline (74.709 us; speedup 1.0000x reference)
//
#include <hip/hip_runtime.h>
#include <math.h>

#define LEAK 0.2f
#define LOG2E 1.4426950408889634f

__device__ __forceinline__ void gl_lds16(const float* g, float* l) {
  __builtin_amdgcn_global_load_lds(
      (const __attribute__((address_space(1))) void*)g,
      (__attribute__((address_space(3))) void*)l, 16, 0, 0);
}

// ---------------- Kernel A: hq = qs@(Wq+Wd); hkbT[b][h][j] = ks@(Wk-Wd)+bias ----
__global__ __launch_bounds__(256) void prep_kernel(
    const float* __restrict__ qs, const float* __restrict__ ks,
    const float* __restrict__ W, const float* __restrict__ bias,
    float* __restrict__ hq, float* __restrict__ hkbT) {
  __shared__ float wcomb[64][68];
  __shared__ float xin[64][68];
  const int blk = blockIdx.x;
  const bool qpart = blk < 64;
  const int r0 = (qpart ? blk : blk - 64) * 64;
  const int t = threadIdx.x;
  const float* src = qpart ? qs : ks;
  for (int rep = 0; rep < 16; ++rep) {
    int e = rep * 256 + t;
    int row = e >> 6, col = e & 63;
    float wd = W[(128 + row) * 64 + col];
    float wm = qpart ? (W[row * 64 + col] + wd)
                     : (W[(64 + row) * 64 + col] - wd);
    wcomb[row][col] = wm;
    xin[row][col] = src[(r0 + row) * 64 + col];
  }
  __syncthreads();
  const int r = t >> 2;
  const int h0 = (t & 3) << 4;
  float acc[16];
#pragma unroll
  for (int k = 0; k < 16; ++k) acc[k] = 0.f;
#pragma unroll 8
  for (int d = 0; d < 64; ++d) {
    float xv = xin[r][d];
#pragma unroll
    for (int c = 0; c < 4; ++c) {
      float4 w4 = *(const float4*)&wcomb[d][h0 + (c << 2)];
      acc[c * 4 + 0] = fmaf(xv, w4.x, acc[c * 4 + 0]);
      acc[c * 4 + 1] = fmaf(xv, w4.y, acc[c * 4 + 1]);
      acc[c * 4 + 2] = fmaf(xv, w4.z, acc[c * 4 + 2]);
      acc[c * 4 + 3] = fmaf(xv, w4.w, acc[c * 4 + 3]);
    }
  }
  int grow = r0 + r;
  if (qpart) {
#pragma unroll
    for (int c = 0; c < 4; ++c) {
      float4 o;
      o.x = acc[c * 4 + 0]; o.y = acc[c * 4 + 1];
      o.z = acc[c * 4 + 2]; o.w = acc[c * 4 + 3];
      *(float4*)&hq[grow * 64 + h0 + (c << 2)] = o;
    }
  } else {
    int bidx = grow >> 10;
    int j = grow & 1023;
#pragma unroll
    for (int k = 0; k < 16; ++k)
      hkbT[(bidx * 64 + h0 + k) * 1024 + j] = acc[k] + bias[h0 + k];
  }
}

// ---------------- Kernel B: flash-style scores/softmax/PV -----------------------
__global__ __launch_bounds__(256, 2) void attn_kernel(
    const float* __restrict__ vs, const float* __restrict__ a,
    const float* __restrict__ hq, const float* __restrict__ hkbT,
    float* __restrict__ out) {
  __shared__ float Tf[64 * 256];    // 64KB: hkbT tile [64h][256j]  OR  v tile [256j][64d]
  __shared__ float pbuf[4][4][64];  // [wave][c][lane]: p for j_local = 4*lane + c
  __shared__ float hqs[4][64];
  __shared__ float asc[64];
  const int t = threadIdx.x;
  const int lane = t & 63;
  const int w = t >> 6;
  const int b = blockIdx.y;
  const int i = blockIdx.x * 4 + w;

  hqs[w][lane] = hq[(b * 1024 + i) * 64 + lane];
  if (t < 64) asc[t] = a[t] * 0.125f;  // fold norm = 1/sqrt(64) into a
  __syncthreads();

  const float* hkb_b = hkbT + b * (64 * 1024);
  const float* v_b = vs + b * (1024 * 64);

  float m = -INFINITY, l = 0.f;
  float o4[4] = {0.f, 0.f, 0.f, 0.f};
  const int dq = (lane & 15) << 2;
  const int jsub = lane >> 4;

  for (int jt = 0; jt < 4; ++jt) {
    // stage hkbT tile: wave w stages rows h = w*16 .. w*16+15 (1KB each, linear)
#pragma unroll
    for (int k = 0; k < 16; ++k) {
      int h = w * 16 + k;
      gl_lds16(hkb_b + h * 1024 + jt * 256 + (lane << 2), &Tf[h * 256]);
    }
    __syncthreads();

    // scores: lane owns j_local = 4*lane + {0..3}
    float s0 = 0.f, s1 = 0.f, s2 = 0.f, s3 = 0.f;
    const float* hqrow = hqs[w];
#pragma unroll 4
    for (int h = 0; h < 64; h += 4) {
      float4 q4 = *(const float4*)&hqrow[h];
      float4 a4 = *(const float4*)&asc[h];
#pragma unroll
      for (int c = 0; c < 4; ++c) {
        float qh = (c == 0) ? q4.x : (c == 1) ? q4.y : (c == 2) ? q4.z : q4.w;
        float ah = (c == 0) ? a4.x : (c == 1) ? a4.y : (c == 2) ? a4.z : a4.w;
        float4 k4 = *(const float4*)&Tf[(h + c) * 256 + (lane << 2)];
        float x0 = qh + k4.x; s0 = fmaf(ah, fmaxf(x0, LEAK * x0), s0);
        float x1 = qh + k4.y; s1 = fmaf(ah, fmaxf(x1, LEAK * x1), s1);
        float x2 = qh + k4.z; s2 = fmaf(ah, fmaxf(x2, LEAK * x2), s2);
        float x3 = qh + k4.w; s3 = fmaf(ah, fmaxf(x3, LEAK * x3), s3);
      }
    }

    // online softmax (per wave)
    float tmax = fmaxf(fmaxf(s0, s1), fmaxf(s2, s3));
#pragma unroll
    for (int off = 32; off >= 1; off >>= 1)
      tmax = fmaxf(tmax, __shfl_xor(tmax, off));
    float mnew = fmaxf(m, tmax);
    float scale = exp2f((m - mnew) * LOG2E);
    float p0 = exp2f((s0 - mnew) * LOG2E);
    float p1 = exp2f((s1 - mnew) * LOG2E);
    float p2 = exp2f((s2 - mnew) * LOG2E);
    float p3 = exp2f((s3 - mnew) * LOG2E);
    float psum = (p0 + p1) + (p2 + p3);
#pragma unroll
    for (int off = 32; off >= 1; off >>= 1)
      psum += __shfl_xor(psum, off);
    l = l * scale + psum;
    m = mnew;
    o4[0] *= scale; o4[1] *= scale; o4[2] *= scale; o4[3] *= scale;
    pbuf[w][0][lane] = p0;
    pbuf[w][1][lane] = p1;
    pbuf[w][2][lane] = p2;
    pbuf[w][3][lane] = p3;
    __syncthreads();

    // stage v tile into same LDS region: [256j][64d] = linear 64KB copy
#pragma unroll
    for (int k = 0; k < 16; ++k) {
      int cchunk = w * 16 + k;
      gl_lds16(v_b + jt * 256 * 64 + cchunk * 256 + (lane << 2), &Tf[cchunk * 256]);
    }
    __syncthreads();

    // PV: lane covers (jsub = lane>>4, d-quad = 4*(lane&15))
    const float* prow = pbuf[w][jsub];
#pragma unroll 4
    for (int g4 = 0; g4 < 64; g4 += 4) {
      float4 pb = *(const float4*)&prow[g4];
#pragma unroll
      for (int gg = 0; gg < 4; ++gg) {
        int jl = ((g4 + gg) << 2) + jsub;
        float pv = (gg == 0) ? pb.x : (gg == 1) ? pb.y : (gg == 2) ? pb.z : pb.w;
        float4 v4 = *(const float4*)&Tf[jl * 64 + dq];
        o4[0] = fmaf(pv, v4.x, o4[0]);
        o4[1] = fmaf(pv, v4.y, o4[1]);
        o4[2] = fmaf(pv, v4.z, o4[2]);
        o4[3] = fmaf(pv, v4.w, o4[3]);
      }
    }
    __syncthreads();  // PV reads done before next tile's staging overwrites Tf
  }

  // reduce partial O across the 4 j-subgroups (lanes ^16, ^32)
#pragma unroll
  for (int c = 0; c < 4; ++c) {
    o4[c] += __shfl_xor(o4[c], 16);
    o4[c] += __shfl_xor(o4[c], 32);
  }
  if (lane < 16) {
    float inv = 1.f / l;
    float4 o;
    o.x = o4[0] * inv; o.y = o4[1] * inv; o.z = o4[2] * inv; o.w = o4[3] * inv;
    *(float4*)&out[(b * 1024 + i) * 64 + dq] = o;
  }
}

extern "C" void kernel_launch(void* const* d_in, const int* in_sizes, int n_in,
                              void* d_out, int out_size, void* d_ws, size_t ws_size,
                              hipStream_t stream) {
  const float* qs = (const float*)d_in[0];
  const float* ks = (const float*)d_in[1];
  const float* vs = (const float*)d_in[2];
  const float* W  = (const float*)d_in[3];
  const float* bi = (const float*)d_in[4];
  const float* a  = (const float*)d_in[5];
  float* out = (float*)d_out;
  float* hq = (float*)d_ws;                 // 4096*64 f32 = 1MB
  float* hkbT = hq + 4096 * 64;             // 4*64*1024 f32 = 1MB
  prep_kernel<<<128, 256, 0, stream>>>(qs, ks, W, bi, hq, hkbT);
  attn_kernel<<<dim3(256, 4), 256, 0, stream>>>(vs, a, hq, hkbT, out);
}

// Round 2
// 42.957 us; speedup vs baseline: 1.7392x; 1.7392x over previous
//
#include <hip/hip_runtime.h>
#include <math.h>

#define LOG2E 1.4426950408889634f
// lrelu(x) = 0.6x + 0.4|x|; norm = 0.125; 0.6*norm = 0.075; 0.4*norm = 0.05

// ---------------- Kernel A: hq = qs@(Wq+Wd); hkbT[b][h][j] = ks@(Wk-Wd)+bias;
// ----------------           Ci = 0.075*(a . hq_row); Dj = 0.075*(a . hkb_row)
__global__ __launch_bounds__(256) void prep_kernel(
    const float* __restrict__ qs, const float* __restrict__ ks,
    const float* __restrict__ W, const float* __restrict__ bias,
    const float* __restrict__ a,
    float* __restrict__ hq, float* __restrict__ hkbT,
    float* __restrict__ Ci, float* __restrict__ Dj) {
  __shared__ __align__(16) float wcomb[64][68];
  __shared__ __align__(16) float xin[64][68];
  const int blk = blockIdx.x;
  const bool qpart = blk < 64;
  const int r0 = (qpart ? blk : blk - 64) * 64;
  const int t = threadIdx.x;
  const float* src = qpart ? qs : ks;
  for (int rep = 0; rep < 16; ++rep) {
    int e = rep * 256 + t;
    int row = e >> 6, col = e & 63;
    float wd = W[(128 + row) * 64 + col];
    float wm = qpart ? (W[row * 64 + col] + wd)
                     : (W[(64 + row) * 64 + col] - wd);
    wcomb[row][col] = wm;
    xin[row][col] = src[(r0 + row) * 64 + col];
  }
  __syncthreads();
  const int r = t >> 2;
  const int h0 = (t & 3) << 4;
  float acc[16];
#pragma unroll
  for (int k = 0; k < 16; ++k) acc[k] = 0.f;
#pragma unroll 8
  for (int d = 0; d < 64; ++d) {
    float xv = xin[r][d];
#pragma unroll
    for (int c = 0; c < 4; ++c) {
      float4 w4 = *(const float4*)&wcomb[d][h0 + (c << 2)];
      acc[c * 4 + 0] = fmaf(xv, w4.x, acc[c * 4 + 0]);
      acc[c * 4 + 1] = fmaf(xv, w4.y, acc[c * 4 + 1]);
      acc[c * 4 + 2] = fmaf(xv, w4.z, acc[c * 4 + 2]);
      acc[c * 4 + 3] = fmaf(xv, w4.w, acc[c * 4 + 3]);
    }
  }
  int grow = r0 + r;
  if (qpart) {
#pragma unroll
    for (int c = 0; c < 4; ++c) {
      float4 o;
      o.x = acc[c * 4 + 0]; o.y = acc[c * 4 + 1];
      o.z = acc[c * 4 + 2]; o.w = acc[c * 4 + 3];
      *(float4*)&hq[grow * 64 + h0 + (c << 2)] = o;
    }
    float part = 0.f;
#pragma unroll
    for (int k = 0; k < 16; ++k) part += a[h0 + k] * acc[k];
    part += __shfl_xor(part, 1);
    part += __shfl_xor(part, 2);
    if ((t & 3) == 0) Ci[grow] = 0.075f * part;
  } else {
    int bidx = grow >> 10;
    int j = grow & 1023;
    float part = 0.f;
#pragma unroll
    for (int k = 0; k < 16; ++k) {
      float v = acc[k] + bias[h0 + k];
      hkbT[(bidx * 64 + h0 + k) * 1024 + j] = v;
      part += a[h0 + k] * v;
    }
    part += __shfl_xor(part, 1);
    part += __shfl_xor(part, 2);
    if ((t & 3) == 0) Dj[bidx * 1024 + j] = 0.075f * part;
  }
}

// ---------------- Kernel B: scores (k from L2, regs), exact softmax, PV from L2
__global__ __launch_bounds__(256, 2) void attn2_kernel(
    const float* __restrict__ vs, const float* __restrict__ a,
    const float* __restrict__ hq, const float* __restrict__ hkbT,
    const float* __restrict__ Ci, const float* __restrict__ Dj,
    float* __restrict__ out) {
  __shared__ __align__(16) float plds[1024 * 8];  // 32KB: p[j'][8r]; reused as obuf
  __shared__ __align__(16) float qlds[8 * 64];    // 2KB
  __shared__ __align__(16) float ablds[64];
  __shared__ __align__(16) float clds[8];
  __shared__ __align__(16) float redm[8][4];
  __shared__ __align__(16) float redl[8][4];
  __shared__ float lfin[8];

  const int t = threadIdx.x;
  const int lane = t & 63;
  const int w = t >> 6;
  const int b = blockIdx.y;
  const int rowbase = blockIdx.x * 8;

  const float* hq_b = hq + (b * 1024 + rowbase) * 64;
  const float* hkbT_b = hkbT + b * 64 * 1024;
  const float* v_b = vs + b * 1024 * 64;

  {
    float2 v = *(const float2*)(hq_b + t * 2);
    *(float2*)&qlds[t * 2] = v;
  }
  if (t < 64) ablds[t] = 0.05f * a[t];
  if (t < 8) clds[t] = Ci[b * 1024 + rowbase + t];
  __syncthreads();

  const int jj = w * 256 + lane * 4;  // lane's first j (owns jj..jj+3)
  float d4[4];
  {
    float4 dv = *(const float4*)(Dj + b * 1024 + jj);
    d4[0] = dv.x; d4[1] = dv.y; d4[2] = dv.z; d4[3] = dv.w;
  }

  float s[8][4];
#pragma unroll
  for (int r = 0; r < 8; ++r)
#pragma unroll
    for (int c = 0; c < 4; ++c) s[r][c] = 0.f;

  // ---- scores: s[r][c] += ab_h * |q[r][h] + k[h][c]| ----
#pragma unroll
  for (int slab = 0; slab < 16; ++slab) {
    const int h0 = slab * 4;
    float kk[4][4];
#pragma unroll
    for (int hh = 0; hh < 4; ++hh)
      *(float4*)kk[hh] = *(const float4*)(hkbT_b + (h0 + hh) * 1024 + jj);
    float abv[4];
    *(float4*)abv = *(const float4*)&ablds[h0];
#pragma unroll
    for (int r = 0; r < 8; ++r) {
      float qv[4];
      *(float4*)qv = *(const float4*)&qlds[r * 64 + h0];
#pragma unroll
      for (int hh = 0; hh < 4; ++hh) {
#pragma unroll
        for (int c = 0; c < 4; ++c) {
          float x = qv[hh] + kk[hh][c];
          s[r][c] = fmaf(abv[hh], fabsf(x), s[r][c]);
        }
      }
    }
  }

  // add Ci + Dj
#pragma unroll
  for (int r = 0; r < 8; ++r) {
    float cr = clds[r];
#pragma unroll
    for (int c = 0; c < 4; ++c) s[r][c] += cr + d4[c];
  }

  // ---- exact softmax over j (cross-lane + cross-wave) ----
  float mw[8];
#pragma unroll
  for (int r = 0; r < 8; ++r) {
    float m = fmaxf(fmaxf(s[r][0], s[r][1]), fmaxf(s[r][2], s[r][3]));
#pragma unroll
    for (int off = 32; off >= 1; off >>= 1) m = fmaxf(m, __shfl_xor(m, off));
    mw[r] = m;
  }
  if (lane == 0) {
#pragma unroll
    for (int r = 0; r < 8; ++r) redm[r][w] = mw[r];
  }
  __syncthreads();
  float mx[8];
#pragma unroll
  for (int r = 0; r < 8; ++r) {
    float4 rm = *(const float4*)&redm[r][0];
    mx[r] = fmaxf(fmaxf(rm.x, rm.y), fmaxf(rm.z, rm.w));
  }
  float lw[8];
#pragma unroll
  for (int r = 0; r < 8; ++r) {
    float psum = 0.f;
#pragma unroll
    for (int c = 0; c < 4; ++c) {
      float p = exp2f((s[r][c] - mx[r]) * LOG2E);
      s[r][c] = p;
      psum += p;
    }
#pragma unroll
    for (int off = 32; off >= 1; off >>= 1) psum += __shfl_xor(psum, off);
    lw[r] = psum;
  }
  if (lane == 0) {
#pragma unroll
    for (int r = 0; r < 8; ++r) redl[r][w] = lw[r];
  }
  __syncthreads();
  float ltot[8];
#pragma unroll
  for (int r = 0; r < 8; ++r) {
    float4 rl = *(const float4*)&redl[r][0];
    ltot[r] = (rl.x + rl.y) + (rl.z + rl.w);
  }
  if (t == 0) {
#pragma unroll
    for (int r = 0; r < 8; ++r) lfin[r] = ltot[r];
  }

  // ---- write p to LDS (swizzled j' so b128 writes spread banks) ----
#pragma unroll
  for (int c = 0; c < 4; ++c) {
    int j = jj + c;
    int jp = j ^ ((j >> 2) & 3);
    float4 lo; lo.x = s[0][c]; lo.y = s[1][c]; lo.z = s[2][c]; lo.w = s[3][c];
    float4 hi; hi.x = s[4][c]; hi.y = s[5][c]; hi.z = s[6][c]; hi.w = s[7][c];
    *(float4*)&plds[jp * 8 + 0] = lo;
    *(float4*)&plds[jp * 8 + 4] = hi;
  }
  __syncthreads();

  // ---- PV: v from global (L2), p broadcast from LDS; o[8r][4d] in regs ----
  float o[8][4];
#pragma unroll
  for (int r = 0; r < 8; ++r)
#pragma unroll
    for (int dd = 0; dd < 4; ++dd) o[r][dd] = 0.f;

  const int dq = (lane & 15) * 4;
  const int jsub = lane >> 4;
#pragma unroll 8
  for (int i = 0; i < 64; ++i) {
    int j = w * 256 + i * 4 + jsub;
    float4 v4 = *(const float4*)(v_b + j * 64 + dq);
    int jp = j ^ ((j >> 2) & 3);
    float pv[8];
    *(float4*)&pv[0] = *(const float4*)&plds[jp * 8 + 0];
    *(float4*)&pv[4] = *(const float4*)&plds[jp * 8 + 4];
    float vv[4];
    vv[0] = v4.x; vv[1] = v4.y; vv[2] = v4.z; vv[3] = v4.w;
#pragma unroll
    for (int r = 0; r < 8; ++r) {
#pragma unroll
      for (int dd = 0; dd < 4; ++dd)
        o[r][dd] = fmaf(pv[r], vv[dd], o[r][dd]);
    }
  }
  __syncthreads();  // all plds reads done before obuf reuse

  // reduce across jsub groups (lanes ^16, ^32)
#pragma unroll
  for (int r = 0; r < 8; ++r) {
#pragma unroll
    for (int dd = 0; dd < 4; ++dd) {
      o[r][dd] += __shfl_xor(o[r][dd], 16);
      o[r][dd] += __shfl_xor(o[r][dd], 32);
    }
  }
  // cross-wave partials via LDS (reuse plds)
  float* obuf = plds;  // [4][8][64]
  if (lane < 16) {
#pragma unroll
    for (int r = 0; r < 8; ++r) {
      float4 ov; ov.x = o[r][0]; ov.y = o[r][1]; ov.z = o[r][2]; ov.w = o[r][3];
      *(float4*)&obuf[(w * 8 + r) * 64 + dq] = ov;
    }
  }
  __syncthreads();

  // final sum + normalize + store (2 outputs per thread, coalesced)
  {
    int e = t * 2;
    int r = e >> 6, d = e & 63;
    float2 acc;
    acc.x = 0.f; acc.y = 0.f;
#pragma unroll
    for (int wv = 0; wv < 4; ++wv) {
      float2 pv = *(const float2*)&obuf[(wv * 8 + r) * 64 + d];
      acc.x += pv.x;
      acc.y += pv.y;
    }
    float iv = 1.0f / lfin[r];
    float2 res;
    res.x = acc.x * iv;
    res.y = acc.y * iv;
    *(float2*)&out[(b * 1024 + rowbase) * 64 + e] = res;
  }
}

extern "C" void kernel_launch(void* const* d_in, const int* in_sizes, int n_in,
                              void* d_out, int out_size, void* d_ws, size_t ws_size,
                              hipStream_t stream) {
  const float* qs = (const float*)d_in[0];
  const float* ks = (const float*)d_in[1];
  const float* vs = (const float*)d_in[2];
  const float* W  = (const float*)d_in[3];
  const float* bi = (const float*)d_in[4];
  const float* a  = (const float*)d_in[5];
  float* out = (float*)d_out;
  float* hq   = (float*)d_ws;               // 4096*64 f32 = 1MB
  float* hkbT = hq + 4096 * 64;             // 4*64*1024 f32 = 1MB
  float* Ci   = hkbT + 4 * 64 * 1024;       // 4096 f32 = 16KB
  float* Dj   = Ci + 4096;                  // 4096 f32 = 16KB
  prep_kernel<<<128, 256, 0, stream>>>(qs, ks, W, bi, a, hq, hkbT, Ci, Dj);
  attn2_kernel<<<dim3(128, 4), 256, 0, stream>>>(vs, a, hq, hkbT, Ci, Dj, out);
}